// Round 1
// baseline (194.455 us; speedup 1.0000x reference)
//
#include <hip/hip_runtime.h>
#include <hip/hip_bf16.h>

// Problem constants
#define B_  16
#define H_  4
#define T_  256
#define NN_ 2048
#define D_  256
#define BH_ 64   // B*H

typedef short bf16x8 __attribute__((ext_vector_type(8)));
typedef float f32x4  __attribute__((ext_vector_type(4)));

__device__ __forceinline__ unsigned short f2bf(float x) {
    union { float f; unsigned u; } v; v.f = x;
    unsigned r = v.u + 0x7fffu + ((v.u >> 16) & 1u);   // RTNE, finite inputs
    return (unsigned short)(r >> 16);
}

// ---------------------------------------------------------------------------
// Kernel 1: cos/sin phase table, 256 positions x 1024 freqs (pattern repeats
// with period 1024 along N: [ph_h|ph_w|ph_h|ph_w]).  cs[t*1024+j] = (cos,sin).
// ---------------------------------------------------------------------------
__global__ void build_cs(float2* __restrict__ cs) {
    int idx = blockIdx.x * 256 + threadIdx.x;       // 256*1024 entries
    int t = idx >> 10, j = idx & 1023;
    int blk = j >> 9, f = j & 511;
    float pos = (float)((blk == 0) ? (t >> 4) : (t & 15));   // h or w
    float inv = powf(10000.0f, -(float)f * (1.0f / 512.0f));
    float ph  = pos * inv;
    float ang = (ph - floorf(ph)) * 6.28318530717958647692f;
    float s, c;
    sincosf(ang, &s, &c);
    cs[idx] = make_float2(c, s);
}

// ---------------------------------------------------------------------------
// Kernel 2: scores = RoPE(Q) . RoPE(K)^T / sqrt(N), bf16 MFMA, fp32 accum.
// Per block: one (bh, 128x128) tile; K-loop over 2048 in BK=64 steps.
// RoPE applied in registers during staging (global->reg->LDS).
// ---------------------------------------------------------------------------
__launch_bounds__(512)
__global__ void gemm1(const float* __restrict__ Q, const float* __restrict__ K,
                      const float2* __restrict__ cs, unsigned short* __restrict__ scores) {
    __shared__ __align__(16) unsigned short Als[128 * 72];
    __shared__ __align__(16) unsigned short Bls[128 * 72];

    const int tid  = threadIdx.x;
    const int bh   = blockIdx.x >> 2;
    const int tile = blockIdx.x & 3;
    const int ti = (tile >> 1) << 7;
    const int si = (tile & 1) << 7;

    const float* Qb = Q + (size_t)bh * (T_ * NN_);
    const float* Kb = K + (size_t)bh * (T_ * NN_);

    const int wv = tid >> 6, lane = tid & 63;
    const int lr = lane & 15, lg = lane >> 4;
    const int m0 = (wv >> 2) * 64;   // 2 wave-rows
    const int n0 = (wv & 3) * 32;    // 4 wave-cols

    f32x4 acc[4][2];
#pragma unroll
    for (int i = 0; i < 4; i++)
#pragma unroll
        for (int j = 0; j < 2; j++) acc[i][j] = (f32x4){0.f, 0.f, 0.f, 0.f};

    for (int k0 = 0; k0 < NN_; k0 += 64) {
        // ---- stage A (Q rows) and B (K rows) with fused RoPE ----
#pragma unroll
        for (int i = 0; i < 4; i++) {
            int lin = i * 512 + tid;           // 0..2047
            int row = lin >> 4;
            int c4  = (lin & 15) << 2;         // float col within BK=64
            int n   = k0 + c4;
            {
                int gr = ti + row;
                float4 q = *(const float4*)(Qb + (size_t)gr * NN_ + n);
                const float2* cp = cs + gr * 1024 + (n & 1023);
                float4 cs01 = *(const float4*)(cp);        // c0,s0,c1,s1
                float4 cs23 = *(const float4*)(cp + 2);    // c2,s2,c3,s3
                ushort4 o;
                o.x = f2bf(q.x * cs01.x - q.y * cs01.y);
                o.y = f2bf(q.y * cs01.z + q.x * cs01.w);
                o.z = f2bf(q.z * cs23.x - q.w * cs23.y);
                o.w = f2bf(q.w * cs23.z + q.z * cs23.w);
                *(ushort4*)(&Als[row * 72 + c4]) = o;
            }
            {
                int gr = si + row;
                float4 q = *(const float4*)(Kb + (size_t)gr * NN_ + n);
                const float2* cp = cs + gr * 1024 + (n & 1023);
                float4 cs01 = *(const float4*)(cp);
                float4 cs23 = *(const float4*)(cp + 2);
                ushort4 o;
                o.x = f2bf(q.x * cs01.x - q.y * cs01.y);
                o.y = f2bf(q.y * cs01.z + q.x * cs01.w);
                o.z = f2bf(q.z * cs23.x - q.w * cs23.y);
                o.w = f2bf(q.w * cs23.z + q.z * cs23.w);
                *(ushort4*)(&Bls[row * 72 + c4]) = o;
            }
        }
        __syncthreads();

        // ---- MFMA over this K-slab ----
#pragma unroll
        for (int kk = 0; kk < 64; kk += 32) {
            bf16x8 af[4], bfr[2];
#pragma unroll
            for (int mi = 0; mi < 4; mi++)
                af[mi] = *(const bf16x8*)(&Als[(m0 + mi * 16 + lr) * 72 + kk + lg * 8]);
#pragma unroll
            for (int ni = 0; ni < 2; ni++)
                bfr[ni] = *(const bf16x8*)(&Bls[(n0 + ni * 16 + lr) * 72 + kk + lg * 8]);
#pragma unroll
            for (int mi = 0; mi < 4; mi++)
#pragma unroll
                for (int ni = 0; ni < 2; ni++)
                    acc[mi][ni] = __builtin_amdgcn_mfma_f32_16x16x32_bf16(
                        af[mi], bfr[ni], acc[mi][ni], 0, 0, 0);
        }
        __syncthreads();
    }

    // ---- epilogue: scale, cast bf16, store scores[bh][t][s] ----
    const float rs = 0.02209708691207961f;   // 1/sqrt(2048)
    unsigned short* sb = scores + (size_t)bh * (T_ * T_);
#pragma unroll
    for (int mi = 0; mi < 4; mi++) {
        int tr = ti + m0 + mi * 16 + lg * 4;
#pragma unroll
        for (int ni = 0; ni < 2; ni++) {
            int sc = si + n0 + ni * 16 + lr;
#pragma unroll
            for (int r = 0; r < 4; r++)
                sb[(size_t)(tr + r) * 256 + sc] = f2bf(acc[mi][ni][r] * rs);
        }
    }
}

// ---------------------------------------------------------------------------
// Kernel 3: out = scores @ V  (V broadcast over H, cast to bf16 in staging).
// A = scores[t][s] bf16 row-major; B staged transposed: Vt_lds[d][s].
// ---------------------------------------------------------------------------
__launch_bounds__(512)
__global__ void gemm2(const unsigned short* __restrict__ scores,
                      const float* __restrict__ V, float* __restrict__ out) {
    __shared__ __align__(16) unsigned short Als[128 * 72];
    __shared__ __align__(16) unsigned short Bls[128 * 72];   // Vt [d][s]

    const int tid  = threadIdx.x;
    const int bh   = blockIdx.x >> 2;
    const int b    = bh >> 2;
    const int tile = blockIdx.x & 3;
    const int ti = (tile >> 1) << 7;
    const int d0 = (tile & 1) << 7;

    const unsigned short* Sb = scores + (size_t)bh * (256 * 256);
    const float* Vb = V + (size_t)b * (256 * 256);

    const int wv = tid >> 6, lane = tid & 63;
    const int lr = lane & 15, lg = lane >> 4;
    const int m0 = (wv >> 2) * 64;
    const int n0 = (wv & 3) * 32;

    f32x4 acc[4][2];
#pragma unroll
    for (int i = 0; i < 4; i++)
#pragma unroll
        for (int j = 0; j < 2; j++) acc[i][j] = (f32x4){0.f, 0.f, 0.f, 0.f};

    for (int k0 = 0; k0 < 256; k0 += 64) {
        // A: 128x64 bf16 straight copy
#pragma unroll
        for (int i = 0; i < 2; i++) {
            int lin = i * 512 + tid;           // 0..1023
            int row = lin >> 3;
            int c8  = (lin & 7) << 3;
            *(uint4*)(&Als[row * 72 + c8]) =
                *(const uint4*)(Sb + (size_t)(ti + row) * 256 + k0 + c8);
        }
        // B: V[k0+s][d0+d] fp32 -> bf16, transposed into Bls[d][s]
#pragma unroll
        for (int i = 0; i < 4; i++) {
            int lin  = i * 512 + tid;          // 0..2047
            int srow = lin >> 5;
            int c4   = (lin & 31) << 2;
            float4 v = *(const float4*)(Vb + (size_t)(k0 + srow) * 256 + d0 + c4);
            Bls[(c4 + 0) * 72 + srow] = f2bf(v.x);
            Bls[(c4 + 1) * 72 + srow] = f2bf(v.y);
            Bls[(c4 + 2) * 72 + srow] = f2bf(v.z);
            Bls[(c4 + 3) * 72 + srow] = f2bf(v.w);
        }
        __syncthreads();

#pragma unroll
        for (int kk = 0; kk < 64; kk += 32) {
            bf16x8 af[4], bfr[2];
#pragma unroll
            for (int mi = 0; mi < 4; mi++)
                af[mi] = *(const bf16x8*)(&Als[(m0 + mi * 16 + lr) * 72 + kk + lg * 8]);
#pragma unroll
            for (int ni = 0; ni < 2; ni++)
                bfr[ni] = *(const bf16x8*)(&Bls[(n0 + ni * 16 + lr) * 72 + kk + lg * 8]);
#pragma unroll
            for (int mi = 0; mi < 4; mi++)
#pragma unroll
                for (int ni = 0; ni < 2; ni++)
                    acc[mi][ni] = __builtin_amdgcn_mfma_f32_16x16x32_bf16(
                        af[mi], bfr[ni], acc[mi][ni], 0, 0, 0);
        }
        __syncthreads();
    }

    float* ob = out + (size_t)bh * (256 * 256);
#pragma unroll
    for (int mi = 0; mi < 4; mi++) {
        int tr = ti + m0 + mi * 16 + lg * 4;
#pragma unroll
        for (int ni = 0; ni < 2; ni++) {
            int dc = d0 + n0 + ni * 16 + lr;
#pragma unroll
            for (int r = 0; r < 4; r++)
                ob[(size_t)(tr + r) * 256 + dc] = acc[mi][ni][r];
        }
    }
}

// ---------------------------------------------------------------------------
extern "C" void kernel_launch(void* const* d_in, const int* in_sizes, int n_in,
                              void* d_out, int out_size, void* d_ws, size_t ws_size,
                              hipStream_t stream) {
    const float* Q = (const float*)d_in[0];
    const float* K = (const float*)d_in[1];
    const float* V = (const float*)d_in[2];
    float* out = (float*)d_out;

    float2* cs = (float2*)d_ws;                                        // 2 MB
    unsigned short* scores =
        (unsigned short*)((char*)d_ws + (size_t)256 * 1024 * sizeof(float2));  // 8 MB

    build_cs<<<dim3(1024), dim3(256), 0, stream>>>(cs);
    gemm1<<<dim3(256), dim3(512), 0, stream>>>(Q, K, cs, scores);
    gemm2<<<dim3(256), dim3(512), 0, stream>>>(scores, V, out);
}

// Round 2
// 186.582 us; speedup vs baseline: 1.0422x; 1.0422x over previous
//
#include <hip/hip_runtime.h>
#include <hip/hip_bf16.h>

#define B_  16
#define H_  4
#define T_  256
#define NN_ 2048
#define D_  256

typedef short bf16x8 __attribute__((ext_vector_type(8)));
typedef float f32x4  __attribute__((ext_vector_type(4)));

__device__ __forceinline__ unsigned short f2bf(float x) {
    union { float f; unsigned u; } v; v.f = x;
    unsigned r = v.u + 0x7fffu + ((v.u >> 16) & 1u);   // RTNE, finite inputs
    return (unsigned short)(r >> 16);
}

// ---------------------------------------------------------------------------
// cs16[p*512 + f] = (cos,sin)(2*pi*frac(p * 10000^(-f/512))),  p in [0,16).
// RoPE phase for token t, channel n:  pos = (bit9(n)==0) ? t>>4 : t&15,
// f = n & 511  (the [ph_h|ph_w|ph_h|ph_w] layout repeats with period 1024).
// ---------------------------------------------------------------------------
__global__ void build_cs(float2* __restrict__ cs) {
    int idx = blockIdx.x * 256 + threadIdx.x;     // 8192 entries
    int p = idx >> 9, f = idx & 511;
    float inv = powf(10000.0f, -(float)f * (1.0f / 512.0f));
    float ph  = (float)p * inv;
    float ang = (ph - floorf(ph)) * 6.28318530717958647692f;
    float s, c;
    sincosf(ang, &s, &c);
    cs[idx] = make_float2(c, s);
}

// ---------------------------------------------------------------------------
// gemm1: scores = RoPE(Q) . RoPE(K)^T / sqrt(N).  128x128 tile, BK=64,
// 512 threads (8 waves).  Software-pipelined: prefetch Q/K regs one k-step
// ahead; MFMA current LDS buffer; RoPE+write other buffer; ONE barrier/step.
// ---------------------------------------------------------------------------
__launch_bounds__(512)
__global__ void gemm1(const float* __restrict__ Q, const float* __restrict__ K,
                      const float2* __restrict__ cs, unsigned short* __restrict__ scores) {
    __shared__ __align__(16) unsigned short Als[2][128 * 72];
    __shared__ __align__(16) unsigned short Bls[2][128 * 72];

    const int tid  = threadIdx.x;
    const int bh   = blockIdx.x >> 2;
    const int tile = blockIdx.x & 3;
    const int ti = (tile >> 1) << 7;
    const int si = (tile & 1) << 7;

    const float* Qb = Q + (size_t)bh * (T_ * NN_);
    const float* Kb = K + (size_t)bh * (T_ * NN_);

    // fixed staging geometry: 4 iters, each thread one float4 per array
    int ldsOff[4], c4v[4];
    const float* qpA[4]; const float* qpB[4];
    int phA[4], pwA[4], phB[4], pwB[4];
#pragma unroll
    for (int i = 0; i < 4; i++) {
        int lin = i * 512 + tid;          // 0..2047
        int row = lin >> 4;
        int c4  = (lin & 15) << 2;
        ldsOff[i] = row * 72 + c4;
        c4v[i] = c4;
        int grA = ti + row, grB = si + row;
        qpA[i] = Qb + (size_t)grA * NN_ + c4;
        qpB[i] = Kb + (size_t)grB * NN_ + c4;
        phA[i] = grA >> 4; pwA[i] = grA & 15;
        phB[i] = grB >> 4; pwB[i] = grB & 15;
    }

    const int wv = tid >> 6, lane = tid & 63;
    const int lr = lane & 15, lg = lane >> 4;
    const int m0 = (wv >> 2) * 64;
    const int n0 = (wv & 3) * 32;

    f32x4 acc[4][2];
#pragma unroll
    for (int i = 0; i < 4; i++)
#pragma unroll
        for (int j = 0; j < 2; j++) acc[i][j] = (f32x4){0.f, 0.f, 0.f, 0.f};

    float4 qA[4], qB[4];

    auto LOAD = [&](int k0) {
#pragma unroll
        for (int i = 0; i < 4; i++) {
            qA[i] = *(const float4*)(qpA[i] + k0);
            qB[i] = *(const float4*)(qpB[i] + k0);
        }
    };

    auto WRITE = [&](int buf, int k0) {
#pragma unroll
        for (int i = 0; i < 4; i++) {
            int n = k0 + c4v[i];
            int f = n & 511;
            int w = (n >> 9) & 1;
            const float2* cpA = cs + ((w ? pwA[i] : phA[i]) << 9) + f;
            const float2* cpB = cs + ((w ? pwB[i] : phB[i]) << 9) + f;
            float4 a01 = *(const float4*)(cpA);
            float4 a23 = *(const float4*)(cpA + 2);
            float4 b01 = *(const float4*)(cpB);
            float4 b23 = *(const float4*)(cpB + 2);
            ushort4 oa, ob;
            oa.x = f2bf(qA[i].x * a01.x - qA[i].y * a01.y);
            oa.y = f2bf(qA[i].y * a01.z + qA[i].x * a01.w);
            oa.z = f2bf(qA[i].z * a23.x - qA[i].w * a23.y);
            oa.w = f2bf(qA[i].w * a23.z + qA[i].z * a23.w);
            ob.x = f2bf(qB[i].x * b01.x - qB[i].y * b01.y);
            ob.y = f2bf(qB[i].y * b01.z + qB[i].x * b01.w);
            ob.z = f2bf(qB[i].z * b23.x - qB[i].w * b23.y);
            ob.w = f2bf(qB[i].w * b23.z + qB[i].z * b23.w);
            *(ushort4*)(&Als[buf][ldsOff[i]]) = oa;
            *(ushort4*)(&Bls[buf][ldsOff[i]]) = ob;
        }
    };

    auto COMPUTE = [&](int buf) {
#pragma unroll
        for (int kk = 0; kk < 64; kk += 32) {
            bf16x8 af[4], bfr[2];
#pragma unroll
            for (int mi = 0; mi < 4; mi++)
                af[mi] = *(const bf16x8*)(&Als[buf][(m0 + mi * 16 + lr) * 72 + kk + lg * 8]);
#pragma unroll
            for (int ni = 0; ni < 2; ni++)
                bfr[ni] = *(const bf16x8*)(&Bls[buf][(n0 + ni * 16 + lr) * 72 + kk + lg * 8]);
#pragma unroll
            for (int mi = 0; mi < 4; mi++)
#pragma unroll
                for (int ni = 0; ni < 2; ni++)
                    acc[mi][ni] = __builtin_amdgcn_mfma_f32_16x16x32_bf16(
                        af[mi], bfr[ni], acc[mi][ni], 0, 0, 0);
        }
    };

    // prologue
    LOAD(0);
    WRITE(0, 0);
    __syncthreads();

    int cur = 0;
    for (int t = 0; t < 31; t++) {
        LOAD((t + 1) * 64);          // issue next-slab loads (consumed in WRITE)
        COMPUTE(cur);                // MFMA on current buffer (covers latency)
        WRITE(cur ^ 1, (t + 1) * 64);
        __syncthreads();
        cur ^= 1;
    }
    COMPUTE(cur);

    // epilogue: scale, cast bf16, store scores[bh][t][s]
    const float rs = 0.02209708691207961f;   // 1/sqrt(2048)
    unsigned short* sb = scores + (size_t)bh * (T_ * T_);
#pragma unroll
    for (int mi = 0; mi < 4; mi++) {
        int tr = ti + m0 + mi * 16 + lg * 4;
#pragma unroll
        for (int ni = 0; ni < 2; ni++) {
            int sc = si + n0 + ni * 16 + lr;
#pragma unroll
            for (int r = 0; r < 4; r++)
                sb[(size_t)(tr + r) * 256 + sc] = f2bf(acc[mi][ni][r] * rs);
        }
    }
}

// ---------------------------------------------------------------------------
// gemm2: out = scores @ V  (V broadcast over H; bf16-cast + transpose into
// LDS during staging).  Same pipeline, 4 k-steps.
// ---------------------------------------------------------------------------
__launch_bounds__(512)
__global__ void gemm2(const unsigned short* __restrict__ scores,
                      const float* __restrict__ V, float* __restrict__ out) {
    __shared__ __align__(16) unsigned short Als[2][128 * 72];
    __shared__ __align__(16) unsigned short Bls[2][128 * 72];   // Vt [d][s]

    const int tid  = threadIdx.x;
    const int bh   = blockIdx.x >> 2;
    const int b    = bh >> 2;
    const int tile = blockIdx.x & 3;
    const int ti = (tile >> 1) << 7;
    const int d0 = (tile & 1) << 7;

    const unsigned short* Sb = scores + (size_t)bh * (256 * 256);
    const float* Vb = V + (size_t)b * (256 * 256);

    const int wv = tid >> 6, lane = tid & 63;
    const int lr = lane & 15, lg = lane >> 4;
    const int m0 = (wv >> 2) * 64;
    const int n0 = (wv & 3) * 32;

    f32x4 acc[4][2];
#pragma unroll
    for (int i = 0; i < 4; i++)
#pragma unroll
        for (int j = 0; j < 2; j++) acc[i][j] = (f32x4){0.f, 0.f, 0.f, 0.f};

    uint4 sA[2]; float4 vB[4];

    auto LOAD = [&](int k0) {
#pragma unroll
        for (int i = 0; i < 2; i++) {
            int lin = i * 512 + tid;
            int row = lin >> 3;
            int c8  = (lin & 7) << 3;
            sA[i] = *(const uint4*)(Sb + (size_t)(ti + row) * 256 + k0 + c8);
        }
#pragma unroll
        for (int i = 0; i < 4; i++) {
            int lin  = i * 512 + tid;
            int srow = lin >> 5;
            int c4   = (lin & 31) << 2;
            vB[i] = *(const float4*)(Vb + (size_t)(k0 + srow) * 256 + d0 + c4);
        }
    };

    auto WRITE = [&](int buf) {
#pragma unroll
        for (int i = 0; i < 2; i++) {
            int lin = i * 512 + tid;
            int row = lin >> 3;
            int c8  = (lin & 7) << 3;
            *(uint4*)(&Als[buf][row * 72 + c8]) = sA[i];
        }
#pragma unroll
        for (int i = 0; i < 4; i++) {
            int lin  = i * 512 + tid;
            int srow = lin >> 5;
            int c4   = (lin & 31) << 2;
            Bls[buf][(c4 + 0) * 72 + srow] = f2bf(vB[i].x);
            Bls[buf][(c4 + 1) * 72 + srow] = f2bf(vB[i].y);
            Bls[buf][(c4 + 2) * 72 + srow] = f2bf(vB[i].z);
            Bls[buf][(c4 + 3) * 72 + srow] = f2bf(vB[i].w);
        }
    };

    auto COMPUTE = [&](int buf) {
#pragma unroll
        for (int kk = 0; kk < 64; kk += 32) {
            bf16x8 af[4], bfr[2];
#pragma unroll
            for (int mi = 0; mi < 4; mi++)
                af[mi] = *(const bf16x8*)(&Als[buf][(m0 + mi * 16 + lr) * 72 + kk + lg * 8]);
#pragma unroll
            for (int ni = 0; ni < 2; ni++)
                bfr[ni] = *(const bf16x8*)(&Bls[buf][(n0 + ni * 16 + lr) * 72 + kk + lg * 8]);
#pragma unroll
            for (int mi = 0; mi < 4; mi++)
#pragma unroll
                for (int ni = 0; ni < 2; ni++)
                    acc[mi][ni] = __builtin_amdgcn_mfma_f32_16x16x32_bf16(
                        af[mi], bfr[ni], acc[mi][ni], 0, 0, 0);
        }
    };

    LOAD(0);
    WRITE(0);
    __syncthreads();

    int cur = 0;
    for (int t = 0; t < 3; t++) {
        LOAD((t + 1) * 64);
        COMPUTE(cur);
        WRITE(cur ^ 1);
        __syncthreads();
        cur ^= 1;
    }
    COMPUTE(cur);

    float* ob = out + (size_t)bh * (256 * 256);
#pragma unroll
    for (int mi = 0; mi < 4; mi++) {
        int tr = ti + m0 + mi * 16 + lg * 4;
#pragma unroll
        for (int ni = 0; ni < 2; ni++) {
            int dc = d0 + n0 + ni * 16 + lr;
#pragma unroll
            for (int r = 0; r < 4; r++)
                ob[(size_t)(tr + r) * 256 + dc] = acc[mi][ni][r];
        }
    }
}

// ---------------------------------------------------------------------------
extern "C" void kernel_launch(void* const* d_in, const int* in_sizes, int n_in,
                              void* d_out, int out_size, void* d_ws, size_t ws_size,
                              hipStream_t stream) {
    const float* Q = (const float*)d_in[0];
    const float* K = (const float*)d_in[1];
    const float* V = (const float*)d_in[2];
    float* out = (float*)d_out;

    float2* cs = (float2*)d_ws;                               // 64 KB
    unsigned short* scores = (unsigned short*)((char*)d_ws + 65536);  // 8 MB

    build_cs<<<dim3(32), dim3(256), 0, stream>>>(cs);
    gemm1<<<dim3(256), dim3(512), 0, stream>>>(Q, K, cs, scores);
    gemm2<<<dim3(256), dim3(512), 0, stream>>>(scores, V, out);
}

// Round 3
// 155.943 us; speedup vs baseline: 1.2470x; 1.1965x over previous
//
#include <hip/hip_runtime.h>
#include <hip/hip_bf16.h>

#define T_  256
#define NN_ 2048

typedef short bf16x8 __attribute__((ext_vector_type(8)));
typedef float f32x4  __attribute__((ext_vector_type(4)));

__device__ __forceinline__ unsigned short f2bf(float x) {
    union { float f; unsigned u; } v; v.f = x;
    unsigned r = v.u + 0x7fffu + ((v.u >> 16) & 1u);   // RTNE, finite inputs
    return (unsigned short)(r >> 16);
}

__device__ __forceinline__ float bflo(unsigned w) {
    union { unsigned u; float f; } v; v.u = w << 16; return v.f;
}
__device__ __forceinline__ float bfhi(unsigned w) {
    union { unsigned u; float f; } v; v.u = w & 0xffff0000u; return v.f;
}
__device__ __forceinline__ unsigned pkbf(float lo, float hi) {
    union { __hip_bfloat16 h; unsigned short s; } a, b;
    a.h = __float2bfloat16(lo);
    b.h = __float2bfloat16(hi);
    return (unsigned)a.s | ((unsigned)b.s << 16);
}

// ---------------------------------------------------------------------------
// cs[p*512+f] = packed bf16 (cos, sin) of 2*pi*frac(p * 10000^(-f/512)).
// 16 pos x 512 f x 4B = 32 KB -> L1-resident in gemm1.
// Token t, channel n:  pos = (bit9(n)? t&15 : t>>4), f = n & 511.
// ---------------------------------------------------------------------------
__global__ void build_cs(unsigned* __restrict__ cs) {
    int idx = blockIdx.x * 256 + threadIdx.x;     // 8192 entries
    int p = idx >> 9, f = idx & 511;
    float inv = powf(10000.0f, -(float)f * (1.0f / 512.0f));
    float ph  = (float)p * inv;
    float ang = (ph - floorf(ph)) * 6.28318530717958647692f;
    float s, c;
    sincosf(ang, &s, &c);
    cs[idx] = pkbf(c, s);
}

// ---------------------------------------------------------------------------
// gemm1: scores = RoPE(Q) . RoPE(K)^T / sqrt(N).
// 128x64 tile, BK=64, 256 threads (4 waves), 512 blocks -> 2 blocks/CU.
// Depth-2 register prefetch; lgkmcnt-only barrier keeps global loads in
// flight across k-steps (T4).  RoPE fused in staging, bf16 cs table.
// ---------------------------------------------------------------------------
__launch_bounds__(256, 2)
__global__ void gemm1(const float* __restrict__ Q, const float* __restrict__ K,
                      const unsigned* __restrict__ cs, unsigned short* __restrict__ scores) {
    __shared__ __align__(16) unsigned short Als[2][128 * 72];
    __shared__ __align__(16) unsigned short Bls[2][64 * 72];

    const int tid  = threadIdx.x;
    const int bh   = blockIdx.x & 63;
    const int tile = blockIdx.x >> 6;          // 0..7
    const int ti = (tile >> 2) << 7;           // 0 or 128   (Q rows)
    const int si = (tile & 3) << 6;            // 0,64,128,192 (K rows)

    const float* Qb = Q + (size_t)bh * (T_ * NN_);
    const float* Kb = K + (size_t)bh * (T_ * NN_);

    // staging geometry: thread owns 8-float octs.  A: 4 units, B: 2 units.
    const float* qpA[4]; int cshA[4], cswA[4], ldsA[4];
    const float* qpB[2]; int cshB[2], cswB[2], ldsB[2];
#pragma unroll
    for (int i = 0; i < 4; i++) {
        int lin = i * 256 + tid;
        int row = lin >> 3, c8 = (lin & 7) << 3;
        int gr = ti + row;
        qpA[i]  = Qb + (size_t)gr * NN_ + c8;
        cshA[i] = ((gr >> 4) << 9) + c8;       // h-phase table offset
        cswA[i] = ((gr & 15) << 9) + c8;       // w-phase table offset
        ldsA[i] = row * 72 + c8;
    }
#pragma unroll
    for (int i = 0; i < 2; i++) {
        int lin = i * 256 + tid;
        int row = lin >> 3, c8 = (lin & 7) << 3;
        int gr = si + row;
        qpB[i]  = Kb + (size_t)gr * NN_ + c8;
        cshB[i] = ((gr >> 4) << 9) + c8;
        cswB[i] = ((gr & 15) << 9) + c8;
        ldsB[i] = row * 72 + c8;
    }

    const int wv = tid >> 6, lane = tid & 63;
    const int lr = lane & 15, lg = lane >> 4;
    const int m0 = (wv >> 1) * 64;
    const int n0 = (wv & 1) * 32;

    f32x4 acc[4][2];
#pragma unroll
    for (int i = 0; i < 4; i++)
#pragma unroll
        for (int j = 0; j < 2; j++) acc[i][j] = (f32x4){0.f, 0.f, 0.f, 0.f};

    auto LOAD = [&](float4 (&a)[8], float4 (&b)[4], int k0) {
#pragma unroll
        for (int i = 0; i < 4; i++) {
            a[2*i]   = *(const float4*)(qpA[i] + k0);
            a[2*i+1] = *(const float4*)(qpA[i] + k0 + 4);
        }
#pragma unroll
        for (int i = 0; i < 2; i++) {
            b[2*i]   = *(const float4*)(qpB[i] + k0);
            b[2*i+1] = *(const float4*)(qpB[i] + k0 + 4);
        }
    };

    auto WRITE = [&](int buf, const float4 (&a)[8], const float4 (&b)[4], int k0) {
        const int fk = k0 & 511;
        const int w  = (k0 >> 9) & 1;          // wave-uniform h/w selector
#pragma unroll
        for (int i = 0; i < 4; i++) {
            int off = (w ? cswA[i] : cshA[i]) + fk;
            uint4 u0 = *(const uint4*)(cs + off);
            uint4 u1 = *(const uint4*)(cs + off + 4);
            float4 f0 = a[2*i], f1 = a[2*i+1];
            uint4 o;
            o.x = pkbf(f0.x*bflo(u0.x) - f0.y*bfhi(u0.x),
                       f0.y*bflo(u0.y) + f0.x*bfhi(u0.y));
            o.y = pkbf(f0.z*bflo(u0.z) - f0.w*bfhi(u0.z),
                       f0.w*bflo(u0.w) + f0.z*bfhi(u0.w));
            o.z = pkbf(f1.x*bflo(u1.x) - f1.y*bfhi(u1.x),
                       f1.y*bflo(u1.y) + f1.x*bfhi(u1.y));
            o.w = pkbf(f1.z*bflo(u1.z) - f1.w*bfhi(u1.z),
                       f1.w*bflo(u1.w) + f1.z*bfhi(u1.w));
            *(uint4*)(&Als[buf][ldsA[i]]) = o;
        }
#pragma unroll
        for (int i = 0; i < 2; i++) {
            int off = (w ? cswB[i] : cshB[i]) + fk;
            uint4 u0 = *(const uint4*)(cs + off);
            uint4 u1 = *(const uint4*)(cs + off + 4);
            float4 f0 = b[2*i], f1 = b[2*i+1];
            uint4 o;
            o.x = pkbf(f0.x*bflo(u0.x) - f0.y*bfhi(u0.x),
                       f0.y*bflo(u0.y) + f0.x*bfhi(u0.y));
            o.y = pkbf(f0.z*bflo(u0.z) - f0.w*bfhi(u0.z),
                       f0.w*bflo(u0.w) + f0.z*bfhi(u0.w));
            o.z = pkbf(f1.x*bflo(u1.x) - f1.y*bfhi(u1.x),
                       f1.y*bflo(u1.y) + f1.x*bfhi(u1.y));
            o.w = pkbf(f1.z*bflo(u1.z) - f1.w*bfhi(u1.z),
                       f1.w*bflo(u1.w) + f1.z*bfhi(u1.w));
            *(uint4*)(&Bls[buf][ldsB[i]]) = o;
        }
    };

    auto COMPUTE = [&](int buf) {
#pragma unroll
        for (int kk = 0; kk < 64; kk += 32) {
            bf16x8 af[4], bfr[2];
#pragma unroll
            for (int mi = 0; mi < 4; mi++)
                af[mi] = *(const bf16x8*)(&Als[buf][(m0 + mi * 16 + lr) * 72 + kk + lg * 8]);
#pragma unroll
            for (int ni = 0; ni < 2; ni++)
                bfr[ni] = *(const bf16x8*)(&Bls[buf][(n0 + ni * 16 + lr) * 72 + kk + lg * 8]);
#pragma unroll
            for (int mi = 0; mi < 4; mi++)
#pragma unroll
                for (int ni = 0; ni < 2; ni++)
                    acc[mi][ni] = __builtin_amdgcn_mfma_f32_16x16x32_bf16(
                        af[mi], bfr[ni], acc[mi][ni], 0, 0, 0);
        }
    };

    auto BAR = [&]() {
        // drain LDS ops only; global prefetch loads stay in flight (T4)
        asm volatile("s_waitcnt lgkmcnt(0)" ::: "memory");
        __builtin_amdgcn_s_barrier();
        asm volatile("" ::: "memory");
    };

    float4 a0[8], a1[8], b0[4], b1[4];

    LOAD(a0, b0, 0);
    LOAD(a1, b1, 64);
    WRITE(0, a0, b0, 0);
    BAR();

    for (int t2 = 0; t2 < 15; t2++) {
        const int t = t2 * 2;
        LOAD(a0, b0, (t + 2) * 64);     // slab t+2 -> set0
        COMPUTE(0);                     // slab t
        WRITE(1, a1, b1, (t + 1) * 64); // slab t+1 -> buf1
        BAR();
        LOAD(a1, b1, (t + 3) * 64);     // slab t+3 -> set1
        COMPUTE(1);                     // slab t+1
        WRITE(0, a0, b0, (t + 2) * 64); // slab t+2 -> buf0
        BAR();
    }
    // t = 30
    COMPUTE(0);                         // slab 30
    WRITE(1, a1, b1, 31 * 64);          // slab 31
    BAR();
    COMPUTE(1);                         // slab 31

    // epilogue: scale, cast bf16, store scores[bh][t][s]
    const float rs = 0.02209708691207961f;   // 1/sqrt(2048)
    unsigned short* sb = scores + (size_t)bh * (T_ * T_);
#pragma unroll
    for (int mi = 0; mi < 4; mi++) {
        int tr = ti + m0 + mi * 16 + lg * 4;
#pragma unroll
        for (int ni = 0; ni < 2; ni++) {
            int sc = si + n0 + ni * 16 + lr;
#pragma unroll
            for (int r = 0; r < 4; r++)
                sb[(size_t)(tr + r) * 256 + sc] = f2bf(acc[mi][ni][r] * rs);
        }
    }
}

// ---------------------------------------------------------------------------
// gemm2: out = scores @ V  (V broadcast over H; bf16-cast + transpose into
// LDS during staging).  Pipelined, 4 k-steps.  (unchanged from R1)
// ---------------------------------------------------------------------------
__launch_bounds__(512)
__global__ void gemm2(const unsigned short* __restrict__ scores,
                      const float* __restrict__ V, float* __restrict__ out) {
    __shared__ __align__(16) unsigned short Als[2][128 * 72];
    __shared__ __align__(16) unsigned short Bls[2][128 * 72];   // Vt [d][s]

    const int tid  = threadIdx.x;
    const int bh   = blockIdx.x >> 2;
    const int b    = bh >> 2;
    const int tile = blockIdx.x & 3;
    const int ti = (tile >> 1) << 7;
    const int d0 = (tile & 1) << 7;

    const unsigned short* Sb = scores + (size_t)bh * (256 * 256);
    const float* Vb = V + (size_t)b * (256 * 256);

    const int wv = tid >> 6, lane = tid & 63;
    const int lr = lane & 15, lg = lane >> 4;
    const int m0 = (wv >> 2) * 64;
    const int n0 = (wv & 3) * 32;

    f32x4 acc[4][2];
#pragma unroll
    for (int i = 0; i < 4; i++)
#pragma unroll
        for (int j = 0; j < 2; j++) acc[i][j] = (f32x4){0.f, 0.f, 0.f, 0.f};

    uint4 sA[2]; float4 vB[4];

    auto LOAD = [&](int k0) {
#pragma unroll
        for (int i = 0; i < 2; i++) {
            int lin = i * 512 + tid;
            int row = lin >> 3;
            int c8  = (lin & 7) << 3;
            sA[i] = *(const uint4*)(Sb + (size_t)(ti + row) * 256 + k0 + c8);
        }
#pragma unroll
        for (int i = 0; i < 4; i++) {
            int lin  = i * 512 + tid;
            int srow = lin >> 5;
            int c4   = (lin & 31) << 2;
            vB[i] = *(const float4*)(Vb + (size_t)(k0 + srow) * 256 + d0 + c4);
        }
    };

    auto WRITE = [&](int buf) {
#pragma unroll
        for (int i = 0; i < 2; i++) {
            int lin = i * 512 + tid;
            int row = lin >> 3;
            int c8  = (lin & 7) << 3;
            *(uint4*)(&Als[buf][row * 72 + c8]) = sA[i];
        }
#pragma unroll
        for (int i = 0; i < 4; i++) {
            int lin  = i * 512 + tid;
            int srow = lin >> 5;
            int c4   = (lin & 31) << 2;
            Bls[buf][(c4 + 0) * 72 + srow] = f2bf(vB[i].x);
            Bls[buf][(c4 + 1) * 72 + srow] = f2bf(vB[i].y);
            Bls[buf][(c4 + 2) * 72 + srow] = f2bf(vB[i].z);
            Bls[buf][(c4 + 3) * 72 + srow] = f2bf(vB[i].w);
        }
    };

    auto COMPUTE = [&](int buf) {
#pragma unroll
        for (int kk = 0; kk < 64; kk += 32) {
            bf16x8 af[4], bfr[2];
#pragma unroll
            for (int mi = 0; mi < 4; mi++)
                af[mi] = *(const bf16x8*)(&Als[buf][(m0 + mi * 16 + lr) * 72 + kk + lg * 8]);
#pragma unroll
            for (int ni = 0; ni < 2; ni++)
                bfr[ni] = *(const bf16x8*)(&Bls[buf][(n0 + ni * 16 + lr) * 72 + kk + lg * 8]);
#pragma unroll
            for (int mi = 0; mi < 4; mi++)
#pragma unroll
                for (int ni = 0; ni < 2; ni++)
                    acc[mi][ni] = __builtin_amdgcn_mfma_f32_16x16x32_bf16(
                        af[mi], bfr[ni], acc[mi][ni], 0, 0, 0);
        }
    };

    LOAD(0);
    WRITE(0);
    __syncthreads();

    int cur = 0;
    for (int t = 0; t < 3; t++) {
        LOAD((t + 1) * 64);
        COMPUTE(cur);
        WRITE(cur ^ 1);
        __syncthreads();
        cur ^= 1;
    }
    COMPUTE(cur);

    float* ob = out + (size_t)bh * (256 * 256);
#pragma unroll
    for (int mi = 0; mi < 4; mi++) {
        int tr = ti + m0 + mi * 16 + lg * 4;
#pragma unroll
        for (int ni = 0; ni < 2; ni++) {
            int dc = d0 + n0 + ni * 16 + lr;
#pragma unroll
            for (int r = 0; r < 4; r++)
                ob[(size_t)(tr + r) * 256 + dc] = acc[mi][ni][r];
        }
    }
}

// ---------------------------------------------------------------------------
extern "C" void kernel_launch(void* const* d_in, const int* in_sizes, int n_in,
                              void* d_out, int out_size, void* d_ws, size_t ws_size,
                              hipStream_t stream) {
    const float* Q = (const float*)d_in[0];
    const float* K = (const float*)d_in[1];
    const float* V = (const float*)d_in[2];
    float* out = (float*)d_out;

    unsigned* cs = (unsigned*)d_ws;                                   // 32 KB
    unsigned short* scores = (unsigned short*)((char*)d_ws + 32768);  // 8 MB

    build_cs<<<dim3(32), dim3(256), 0, stream>>>(cs);
    gemm1<<<dim3(512), dim3(256), 0, stream>>>(Q, K, cs, scores);
    gemm2<<<dim3(256), dim3(512), 0, stream>>>(scores, V, out);
}